// Round 3
// baseline (110485.364 us; speedup 1.0000x reference)
//
#include <hip/hip_runtime.h>

// ODE_Vanilla scan: B=128, T=256, I=256, H=1024, C=10, fp32.
// R3: single persistent kernel (256 blocks x 512 threads, 1 block/CU,
// co-resident), hand-rolled 2-level grid barrier with __threadfence for
// cross-XCD coherence. Register-blocked 8x8 thread tiles kill the weight
// re-load redundancy that bound R1/R2 (vector path was ~500 B/cyc/CU needed
// vs ~135 available). Split-K S=64 (lane=k-chunk), reduce-scatter butterfly.
// Block tile: 16 rows x 32 cols (RT=8 x CT=32 = 256 blocks). Wave w of 8:
// r-tile = w>>2, c-tile = w&3; lane = k-split index; after reduce lane l owns
// tile element (l>>3, l&7).

constexpr int Bsz = 128, Tn = 256, In = 256, Hn = 1024, Cn = 10;
constexpr float LR = 0.001f;
constexpr int ROWL = 1152;  // 1024 + 4 pad per 32 floats (bank spread, 16B aligned)
#define HADDR(k) ((k) + ((((k) >> 5)) << 2))

// ---- Wh -> Wh^T once per call
__global__ __launch_bounds__(256) void k_transpose(const float* __restrict__ W,
                                                   float* __restrict__ WT) {
  __shared__ float tile[32][33];
  const int bx = blockIdx.x * 32, by = blockIdx.y * 32;
  const int tx = threadIdx.x & 31, ty = threadIdx.x >> 5;
#pragma unroll
  for (int dy = 0; dy < 32; dy += 8)
    tile[ty + dy][tx] = W[(size_t)(by + ty + dy) * Hn + bx + tx];
  __syncthreads();
#pragma unroll
  for (int dy = 0; dy < 32; dy += 8)
    WT[(size_t)(bx + ty + dy) * Hn + by + tx] = tile[tx][ty + dy];
}

// ---- init: out=fc_b, h_cur=hidden, barrier state=0 (ws re-poisoned each call)
__global__ __launch_bounds__(256) void k_init(float* __restrict__ out,
                                              const float* __restrict__ fc_b,
                                              float* __restrict__ h_cur,
                                              const float* __restrict__ hidden,
                                              int* __restrict__ bar) {
  const int i = blockIdx.x * blockDim.x + threadIdx.x;
  if (i < Bsz * Tn * Cn) out[i] = fc_b[i % Cn];
  if (i < Bsz * Hn) h_cur[i] = hidden[i];
  if (i < 192) bar[i] = 0;
}

// ---- 2-level grid barrier: 8 groups x 32 blocks -> root -> generation
// bar: [g*16] group counters (g<8), [128] root, [129] generation
__device__ __forceinline__ void grid_barrier(int* bar, int blk) {
  __syncthreads();
  if (threadIdx.x == 0) {
    __threadfence();  // push this block's stores device-wide (L2 writeback)
    int* gcnt = bar + (blk & 7) * 16;
    int* root = bar + 128;
    int* gen = bar + 129;
    const int g0 = __hip_atomic_load(gen, __ATOMIC_RELAXED, __HIP_MEMORY_SCOPE_AGENT);
    if (__hip_atomic_fetch_add(gcnt, 1, __ATOMIC_RELAXED, __HIP_MEMORY_SCOPE_AGENT) == 31) {
      if (__hip_atomic_fetch_add(root, 1, __ATOMIC_RELAXED, __HIP_MEMORY_SCOPE_AGENT) == 7) {
        // last block of all: reset counters, then release everyone
#pragma unroll
        for (int g = 0; g < 8; g++)
          __hip_atomic_store(bar + g * 16, 0, __ATOMIC_RELAXED, __HIP_MEMORY_SCOPE_AGENT);
        __hip_atomic_store(root, 0, __ATOMIC_RELAXED, __HIP_MEMORY_SCOPE_AGENT);
        __hip_atomic_fetch_add(gen, 1, __ATOMIC_RELEASE, __HIP_MEMORY_SCOPE_AGENT);
      } else {
        while (__hip_atomic_load(gen, __ATOMIC_RELAXED, __HIP_MEMORY_SCOPE_AGENT) == g0)
          __builtin_amdgcn_s_sleep(2);
      }
    } else {
      while (__hip_atomic_load(gen, __ATOMIC_RELAXED, __HIP_MEMORY_SCOPE_AGENT) == g0)
        __builtin_amdgcn_s_sleep(2);
    }
    __threadfence();  // invalidate stale caches before reading others' data
  }
  __syncthreads();
}

// reduce-scatter over 64 lanes: input a[64] of per-lane partials; output:
// lane l returns the full sum of a[l] across all lanes.
__device__ __forceinline__ float reduce_scatter64(float (&a)[64], int lane) {
#pragma unroll
  for (int m = 32; m >= 1; m >>= 1) {
#pragma unroll
    for (int i = 0; i < m; i++) {
      const float send = (lane & m) ? a[i] : a[i + m];
      const float keep = (lane & m) ? a[i + m] : a[i];
      a[i] = keep + __shfl_xor(send, m, 64);
    }
  }
  return a[0];
}

__global__ __launch_bounds__(512, 2) void k_persist(
    const float* __restrict__ X, float* __restrict__ h_cur,
    float* __restrict__ v_buf, const float* __restrict__ Wh,
    const float* __restrict__ Wx, const float* __restrict__ WT,
    const float* __restrict__ bias, const float* __restrict__ alpha,
    const float* __restrict__ fc_w, float* __restrict__ out,
    float* __restrict__ hfin, int* __restrict__ bar) {
  extern __shared__ float sm[];      // 16 rows x ROWL floats = 73,728 B
  __shared__ float hn_s[16][32];
  const int tid = threadIdx.x, blk = blockIdx.x;
  const int lane = tid & 63, w = tid >> 6;
  const int rt = blk >> 5, ct = blk & 31;       // XCD = blk%8 = ct%8 -> 4 ct slices/XCD (L2-resident weights)
  const int rg0 = rt * 16;                      // global row base
  const int c_blk = ct * 32;                    // global col base of block
  const int r0w = (w >> 2) * 8, c0w = (w & 3) * 8;
  const int cg = c_blk + c0w;                   // this thread's 8-col base
  const int rl = r0w + (lane >> 3);             // owned output (after reduce)
  const int cgj = c_blk + c0w + (lane & 7);
  const float av = alpha[0];
  const int kb = lane * 16;                     // k-chunk base (Wh / WT)
  const int kxb = lane * 4;                     // k-chunk base (Wx)

  for (int t = 0; t < Tn; t++) {
    // ---- stage h[rg0..rg0+16)[:] -> sm (swizzled) ----
    {
      const float4* src = (const float4*)(h_cur + (size_t)rg0 * Hn);
#pragma unroll
      for (int u = 0; u < 8; u++) {
        const int f = tid + 512 * u;
        const int row = f >> 8, k = (f & 255) * 4;
        *(float4*)(sm + row * ROWL + HADDR(k)) = src[f];
      }
    }
    __syncthreads();

    // ---- phase 1: pre = h@Wh + x@Wx (split-K over lanes) ----
    float a[64];
#pragma unroll
    for (int i = 0; i < 64; i++) a[i] = 0.f;
    {
      const float* wb = Wh + (size_t)kb * Hn + cg;
#pragma unroll
      for (int g = 0; g < 4; g++) {
        float4 h4[8];
#pragma unroll
        for (int i = 0; i < 8; i++)
          h4[i] = *(const float4*)(sm + (r0w + i) * ROWL + HADDR(kb) + 4 * g);
#pragma unroll
        for (int q = 0; q < 4; q++) {
          const float* wr = wb + (size_t)(4 * g + q) * Hn;
          const float4 wA = *(const float4*)(wr);
          const float4 wB = *(const float4*)(wr + 4);
#pragma unroll
          for (int i = 0; i < 8; i++) {
            const float hv = ((const float*)&h4[i])[q];
            a[i * 8 + 0] = fmaf(hv, wA.x, a[i * 8 + 0]);
            a[i * 8 + 1] = fmaf(hv, wA.y, a[i * 8 + 1]);
            a[i * 8 + 2] = fmaf(hv, wA.z, a[i * 8 + 2]);
            a[i * 8 + 3] = fmaf(hv, wA.w, a[i * 8 + 3]);
            a[i * 8 + 4] = fmaf(hv, wB.x, a[i * 8 + 4]);
            a[i * 8 + 5] = fmaf(hv, wB.y, a[i * 8 + 5]);
            a[i * 8 + 6] = fmaf(hv, wB.z, a[i * 8 + 6]);
            a[i * 8 + 7] = fmaf(hv, wB.w, a[i * 8 + 7]);
          }
        }
      }
    }
    {  // x @ Wx part: 4 k's per lane, x straight from global (L2-hot)
      const float* xw = Wx + (size_t)kxb * Hn + cg;
      float4 x4[8];
#pragma unroll
      for (int i = 0; i < 8; i++)
        x4[i] = *(const float4*)(X + (size_t)(rg0 + r0w + i) * (Tn * In) + t * In + kxb);
#pragma unroll
      for (int q = 0; q < 4; q++) {
        const float* wr = xw + (size_t)q * Hn;
        const float4 wA = *(const float4*)(wr);
        const float4 wB = *(const float4*)(wr + 4);
#pragma unroll
        for (int i = 0; i < 8; i++) {
          const float xv = ((const float*)&x4[i])[q];
          a[i * 8 + 0] = fmaf(xv, wA.x, a[i * 8 + 0]);
          a[i * 8 + 1] = fmaf(xv, wA.y, a[i * 8 + 1]);
          a[i * 8 + 2] = fmaf(xv, wA.z, a[i * 8 + 2]);
          a[i * 8 + 3] = fmaf(xv, wA.w, a[i * 8 + 3]);
          a[i * 8 + 4] = fmaf(xv, wB.x, a[i * 8 + 4]);
          a[i * 8 + 5] = fmaf(xv, wB.y, a[i * 8 + 5]);
          a[i * 8 + 6] = fmaf(xv, wB.z, a[i * 8 + 6]);
          a[i * 8 + 7] = fmaf(xv, wB.w, a[i * 8 + 7]);
        }
      }
    }
    {
      const float pre = reduce_scatter64(a, lane) + bias[cgj];
      const float hold = sm[rl * ROWL + HADDR(cgj)];
      v_buf[(size_t)(rg0 + rl) * Hn + cgj] = av * hold - fmaxf(pre, 0.f);
    }
    grid_barrier(bar, blk);

    // ---- stage v[rg0..rg0+16)[:] -> sm ----
    {
      const float4* src = (const float4*)(v_buf + (size_t)rg0 * Hn);
#pragma unroll
      for (int u = 0; u < 8; u++) {
        const int f = tid + 512 * u;
        const int row = f >> 8, k = (f & 255) * 4;
        *(float4*)(sm + row * ROWL + HADDR(k)) = src[f];
      }
    }
    __syncthreads();

    // ---- phase 2: u = v @ Wh^T ----
#pragma unroll
    for (int i = 0; i < 64; i++) a[i] = 0.f;
    {
      const float* wb = WT + (size_t)kb * Hn + cg;
#pragma unroll
      for (int g = 0; g < 4; g++) {
        float4 v4[8];
#pragma unroll
        for (int i = 0; i < 8; i++)
          v4[i] = *(const float4*)(sm + (r0w + i) * ROWL + HADDR(kb) + 4 * g);
#pragma unroll
        for (int q = 0; q < 4; q++) {
          const float* wr = wb + (size_t)(4 * g + q) * Hn;
          const float4 wA = *(const float4*)(wr);
          const float4 wB = *(const float4*)(wr + 4);
#pragma unroll
          for (int i = 0; i < 8; i++) {
            const float vv = ((const float*)&v4[i])[q];
            a[i * 8 + 0] = fmaf(vv, wA.x, a[i * 8 + 0]);
            a[i * 8 + 1] = fmaf(vv, wA.y, a[i * 8 + 1]);
            a[i * 8 + 2] = fmaf(vv, wA.z, a[i * 8 + 2]);
            a[i * 8 + 3] = fmaf(vv, wA.w, a[i * 8 + 3]);
            a[i * 8 + 4] = fmaf(vv, wB.x, a[i * 8 + 4]);
            a[i * 8 + 5] = fmaf(vv, wB.y, a[i * 8 + 5]);
            a[i * 8 + 6] = fmaf(vv, wB.z, a[i * 8 + 6]);
            a[i * 8 + 7] = fmaf(vv, wB.w, a[i * 8 + 7]);
          }
        }
      }
    }
    {
      const float uu = reduce_scatter64(a, lane);
      const float vv = sm[rl * ROWL + HADDR(cgj)];
      const size_t hidx = (size_t)(rg0 + rl) * Hn + cgj;
      const float hold = h_cur[hidx];
      const float phi = av * hold - vv;  // exact reconstruction
      const float hn = hold - LR * (av * vv - (phi > 0.f ? uu : 0.f));
      h_cur[hidx] = hn;  // in-place safe: each (row,col) owned by one lane
      if (t == Tn - 1) hfin[hidx] = hn;
      hn_s[rl][c0w + (lane & 7)] = hn;
    }
    __syncthreads();
    if (tid < 160) {  // fused FC partial over this block's 32 cols
      const int rr = tid / 10, c = tid % 10;
      float s = 0.f;
#pragma unroll
      for (int j2 = 0; j2 < 32; j2++)
        s += hn_s[rr][j2] * fc_w[(size_t)(c_blk + j2) * Cn + c];
      atomicAdd(&out[((size_t)(rg0 + rr) * Tn + t) * Cn + c], s);
    }
    grid_barrier(bar, blk);
  }
}

extern "C" void kernel_launch(void* const* d_in, const int* in_sizes, int n_in,
                              void* d_out, int out_size, void* d_ws, size_t ws_size,
                              hipStream_t stream) {
  const float* X      = (const float*)d_in[0];
  const float* hidden = (const float*)d_in[1];
  const float* alpha  = (const float*)d_in[2];
  const float* bias   = (const float*)d_in[3];
  const float* Wh     = (const float*)d_in[4];
  const float* Wx     = (const float*)d_in[5];
  const float* fc_w   = (const float*)d_in[6];
  const float* fc_b   = (const float*)d_in[7];
  float* out  = (float*)d_out;
  float* hfin = out + (size_t)Bsz * Tn * Cn;

  char* ws = (char*)d_ws;
  float* WhT   = (float*)ws;                                   // 4 MB
  float* h_cur = (float*)(ws + 4194304);                       // 512 KB
  float* v_buf = (float*)(ws + 4718592);                       // 512 KB
  int*   bar   = (int*)(ws + 5242880);                         // 768 B

  const int lds_bytes = 16 * ROWL * 4;  // 73,728
  hipFuncSetAttribute((const void*)k_persist,
                      hipFuncAttributeMaxDynamicSharedMemorySize, lds_bytes);

  k_transpose<<<dim3(32, 32), 256, 0, stream>>>(Wh, WhT);
  k_init<<<(Bsz * Tn * Cn + 255) / 256, 256, 0, stream>>>(out, fc_b, h_cur,
                                                          hidden, bar);
  k_persist<<<256, 512, lds_bytes, stream>>>(X, h_cur, v_buf, Wh, Wx, WhT, bias,
                                             alpha, fc_w, out, hfin, bar);
}

// Round 4
// 12407.983 us; speedup vs baseline: 8.9044x; 8.9044x over previous
//
#include <hip/hip_runtime.h>

// ODE_Vanilla scan: B=128, T=256, I=256, H=1024, C=10, fp32.
// R4: back to multi-kernel (2 dispatches/step; kernel boundary = grid sync —
// R3 proved per-block __threadfence barriers cost ~215 us each on 8 XCDs).
// Compute core from R3 (verified): 8x8 register tiles, lane = 64-way k-split,
// reduce-scatter butterfly. New: weights pre-packed per 16-col slice so W
// lines are fully consumed; interleaved k-ownership (stride-4 floats) makes
// LDS h-reads conflict-free with a plain (unpadded) 64 KB tile.
// Block: 16 rows x 16 cols, 256 thr = 4 waves (rgrp2 x cgrp2), grid 512.
// ws usage ~10 MB: Whp 4M | WTp 4M | Wxp 1M | h_cur 512K | v_buf 512K.

constexpr int Bsz = 128, Tn = 256, In = 256, Hn = 1024, Cn = 10;
constexpr float LR = 0.001f;

// ---- pack Wh, Wx into [ct][k][16 cols] contiguous slices
__global__ __launch_bounds__(256) void k_pack(const float* __restrict__ Wh,
                                              const float* __restrict__ Wx,
                                              float* __restrict__ Whp,
                                              float* __restrict__ Wxp) {
  const int g = blockIdx.x * 256 + threadIdx.x;  // over 1M elements
  {
    const int k = g >> 10, c = g & 1023;
    Whp[(((size_t)(c >> 4) * Hn + k) << 4) + (c & 15)] = Wh[g];
  }
  if (g < In * Hn) {
    const int k = g >> 10, c = g & 1023;
    Wxp[(((size_t)(c >> 4) * In + k) << 4) + (c & 15)] = Wx[g];
  }
}

// ---- Wh^T, packed directly into [ct][k][16 cols]
__global__ __launch_bounds__(256) void k_transpack(const float* __restrict__ W,
                                                   float* __restrict__ WTp) {
  __shared__ float tile[32][33];
  const int bx = blockIdx.x * 32, by = blockIdx.y * 32;
  const int tx = threadIdx.x & 31, ty = threadIdx.x >> 5;
#pragma unroll
  for (int dy = 0; dy < 32; dy += 8)
    tile[ty + dy][tx] = W[(size_t)(by + ty + dy) * Hn + bx + tx];
  __syncthreads();
#pragma unroll
  for (int dy = 0; dy < 32; dy += 8) {
    const int k = bx + ty + dy, c = by + tx;  // WT[k][c] = W[c][k]
    WTp[(((size_t)(c >> 4) * Hn + k) << 4) + (c & 15)] = tile[tx][ty + dy];
  }
}

__global__ __launch_bounds__(256) void k_init(float* __restrict__ out,
                                              const float* __restrict__ fc_b,
                                              float* __restrict__ h_cur,
                                              const float* __restrict__ hidden) {
  const int i = blockIdx.x * blockDim.x + threadIdx.x;
  if (i < Bsz * Tn * Cn) out[i] = fc_b[i % Cn];
  if (i < Bsz * Hn) h_cur[i] = hidden[i];
}

// reduce-scatter over 64 lanes: lane l ends with full sum of a[l]. (R3-verified)
__device__ __forceinline__ float reduce_scatter64(float (&a)[64], int lane) {
#pragma unroll
  for (int m = 32; m >= 1; m >>= 1) {
#pragma unroll
    for (int i = 0; i < m; i++) {
      const float send = (lane & m) ? a[i] : a[i + m];
      const float keep = (lane & m) ? a[i + m] : a[i];
      a[i] = keep + __shfl_xor(send, m, 64);
    }
  }
  return a[0];
}

#define FMA8(s, wA, wB, base)                          \
  a[(base) + 0] = fmaf((s), (wA).x, a[(base) + 0]);    \
  a[(base) + 1] = fmaf((s), (wA).y, a[(base) + 1]);    \
  a[(base) + 2] = fmaf((s), (wA).z, a[(base) + 2]);    \
  a[(base) + 3] = fmaf((s), (wA).w, a[(base) + 3]);    \
  a[(base) + 4] = fmaf((s), (wB).x, a[(base) + 4]);    \
  a[(base) + 5] = fmaf((s), (wB).y, a[(base) + 5]);    \
  a[(base) + 6] = fmaf((s), (wB).z, a[(base) + 6]);    \
  a[(base) + 7] = fmaf((s), (wB).w, a[(base) + 7]);

// ---- phase 1: v = a*h - relu(h@Wh + x_t@Wx + b)
// grid 512 = rt(8) x ct(64); 256 thr = 4 waves (rgrp2 x cgrp2); lane = k-split
__global__ __launch_bounds__(256, 2) void k_phase1(
    const float* __restrict__ h, const float* __restrict__ X,
    const float* __restrict__ Whp, const float* __restrict__ Wxp,
    const float* __restrict__ bias, const float* __restrict__ alpha,
    float* __restrict__ v_out, int t) {
  extern __shared__ float h_s[];  // [16][1024] = 64 KB, plain layout
  const int tid = threadIdx.x, lane = tid & 63, w = tid >> 6;
  const int rt = blockIdx.x >> 6, ct = blockIdx.x & 63;
  const int rg0 = rt * 16, c_blk = ct * 16;
  const int r0w = (w >> 1) * 8, c0w = (w & 1) * 8;
  {  // stage 16 h rows (16384 contiguous floats)
    const float4* src = (const float4*)(h + (size_t)rg0 * Hn);
    float4* dst = (float4*)h_s;
#pragma unroll
    for (int u = 0; u < 16; u++) dst[tid + 256 * u] = src[tid + 256 * u];
  }
  __syncthreads();

  float a[64];
#pragma unroll
  for (int i = 0; i < 64; i++) a[i] = 0.f;

  {  // h @ Wh: lane owns k in {4*lane + 256*j + q}
    const float* Wb = Whp + ((size_t)ct * Hn << 4) + c0w;
#pragma unroll
    for (int j = 0; j < 4; j++) {
      const int kb = 4 * lane + 256 * j;
      float4 h4[8];
#pragma unroll
      for (int i = 0; i < 8; i++)
        h4[i] = *(const float4*)(h_s + (r0w + i) * Hn + kb);
#pragma unroll
      for (int q = 0; q < 4; q++) {
        const float* wr = Wb + ((size_t)(kb + q) << 4);
        const float4 wA = *(const float4*)(wr);
        const float4 wB = *(const float4*)(wr + 4);
#pragma unroll
        for (int i = 0; i < 8; i++) {
          const float hv = ((const float*)&h4[i])[q];
          FMA8(hv, wA, wB, i * 8);
        }
      }
    }
  }
  {  // x_t @ Wx: lane owns k2 in {4*lane + q}, coalesced X float4 per row
    const int kb = 4 * lane;
    float4 x4[8];
#pragma unroll
    for (int i = 0; i < 8; i++)
      x4[i] = *(const float4*)(X + ((size_t)(rg0 + r0w + i) * Tn + t) * In + kb);
    const float* Wb = Wxp + ((size_t)ct * In << 4) + c0w;
#pragma unroll
    for (int q = 0; q < 4; q++) {
      const float* wr = Wb + ((size_t)(kb + q) << 4);
      const float4 wA = *(const float4*)(wr);
      const float4 wB = *(const float4*)(wr + 4);
#pragma unroll
      for (int i = 0; i < 8; i++) {
        const float xv = ((const float*)&x4[i])[q];
        FMA8(xv, wA, wB, i * 8);
      }
    }
  }
  const float red = reduce_scatter64(a, lane);  // lane owns (lane>>3, lane&7)
  const int rl = r0w + (lane >> 3);
  const int cg = c_blk + c0w + (lane & 7);
  const float av = alpha[0];
  const float pre = red + bias[cg];
  const float hold = h_s[rl * Hn + cg];
  v_out[(size_t)(rg0 + rl) * Hn + cg] = av * hold - fmaxf(pre, 0.f);
}

// ---- phase 2: u = v@Wh^T; h update; fused FC partial
__global__ __launch_bounds__(256, 2) void k_phase2(
    float* __restrict__ h, const float* __restrict__ v_in,
    const float* __restrict__ WTp, const float* __restrict__ alpha,
    const float* __restrict__ fc_w, float* __restrict__ out,
    float* __restrict__ hfin, int t, int last) {
  extern __shared__ float v_s[];  // [16][1024]
  __shared__ float hn_s[16][16];
  const int tid = threadIdx.x, lane = tid & 63, w = tid >> 6;
  const int rt = blockIdx.x >> 6, ct = blockIdx.x & 63;
  const int rg0 = rt * 16, c_blk = ct * 16;
  const int r0w = (w >> 1) * 8, c0w = (w & 1) * 8;
  {
    const float4* src = (const float4*)(v_in + (size_t)rg0 * Hn);
    float4* dst = (float4*)v_s;
#pragma unroll
    for (int u = 0; u < 16; u++) dst[tid + 256 * u] = src[tid + 256 * u];
  }
  __syncthreads();

  float a[64];
#pragma unroll
  for (int i = 0; i < 64; i++) a[i] = 0.f;
  {
    const float* Wb = WTp + ((size_t)ct * Hn << 4) + c0w;
#pragma unroll
    for (int j = 0; j < 4; j++) {
      const int kb = 4 * lane + 256 * j;
      float4 v4[8];
#pragma unroll
      for (int i = 0; i < 8; i++)
        v4[i] = *(const float4*)(v_s + (r0w + i) * Hn + kb);
#pragma unroll
      for (int q = 0; q < 4; q++) {
        const float* wr = Wb + ((size_t)(kb + q) << 4);
        const float4 wA = *(const float4*)(wr);
        const float4 wB = *(const float4*)(wr + 4);
#pragma unroll
        for (int i = 0; i < 8; i++) {
          const float vv = ((const float*)&v4[i])[q];
          FMA8(vv, wA, wB, i * 8);
        }
      }
    }
  }
  const float uu = reduce_scatter64(a, lane);
  const int rl = r0w + (lane >> 3);
  const int cl = c0w + (lane & 7);
  const int cg = c_blk + cl;
  const float av = alpha[0];
  const float vv = v_s[rl * Hn + cg];
  const size_t hidx = (size_t)(rg0 + rl) * Hn + cg;
  const float hold = h[hidx];
  const float phi = av * hold - vv;  // exact reconstruction of phase-1 phi
  const float hn = hold - LR * (av * vv - (phi > 0.f ? uu : 0.f));
  h[hidx] = hn;  // in-place safe: one owner per element
  if (last) hfin[hidx] = hn;
  hn_s[rl][cl] = hn;
  __syncthreads();
  if (tid < 160) {  // FC partial over this block's 16 cols -> 160 atomics
    const int rr = tid / 10, c = tid % 10;
    float s = 0.f;
#pragma unroll
    for (int jj = 0; jj < 16; jj++)
      s += hn_s[rr][jj] * fc_w[(size_t)(c_blk + jj) * Cn + c];
    atomicAdd(&out[((size_t)(rg0 + rr) * Tn + t) * Cn + c], s);
  }
}

extern "C" void kernel_launch(void* const* d_in, const int* in_sizes, int n_in,
                              void* d_out, int out_size, void* d_ws, size_t ws_size,
                              hipStream_t stream) {
  const float* X      = (const float*)d_in[0];
  const float* hidden = (const float*)d_in[1];
  const float* alpha  = (const float*)d_in[2];
  const float* bias   = (const float*)d_in[3];
  const float* Wh     = (const float*)d_in[4];
  const float* Wx     = (const float*)d_in[5];
  const float* fc_w   = (const float*)d_in[6];
  const float* fc_b   = (const float*)d_in[7];
  float* out  = (float*)d_out;
  float* hfin = out + (size_t)Bsz * Tn * Cn;

  char* ws = (char*)d_ws;
  float* Whp   = (float*)(ws);             // 4 MB
  float* WTp   = (float*)(ws + (4u << 20));  // 4 MB
  float* Wxp   = (float*)(ws + (8u << 20));  // 1 MB
  float* h_cur = (float*)(ws + (9u << 20));  // 512 KB
  float* v_buf = (float*)(ws + (9u << 20) + (512u << 10));

  const int lds1 = 16 * Hn * 4;  // 64 KB dynamic
  hipFuncSetAttribute((const void*)k_phase1,
                      hipFuncAttributeMaxDynamicSharedMemorySize, lds1);
  hipFuncSetAttribute((const void*)k_phase2,
                      hipFuncAttributeMaxDynamicSharedMemorySize, lds1);

  k_pack<<<4096, 256, 0, stream>>>(Wh, Wx, Whp, Wxp);
  k_transpack<<<dim3(32, 32), 256, 0, stream>>>(Wh, WTp);
  k_init<<<(Bsz * Tn * Cn + 255) / 256, 256, 0, stream>>>(out, fc_b, h_cur, hidden);
  for (int t = 0; t < Tn; t++) {
    k_phase1<<<512, 256, lds1, stream>>>(h_cur, X, Whp, Wxp, bias, alpha, v_buf, t);
    k_phase2<<<512, 256, lds1, stream>>>(h_cur, v_buf, WTp, alpha, fc_w, out, hfin,
                                         t, t == Tn - 1);
  }
}